// Round 7
// baseline (331.154 us; speedup 1.0000x reference)
//
#include <hip/hip_runtime.h>
#include <hip/hip_bf16.h>

typedef short bf16x8 __attribute__((ext_vector_type(8)));
typedef float f32x4 __attribute__((ext_vector_type(4)));

typedef __attribute__((address_space(3))) void as3_void;
typedef const __attribute__((address_space(1))) void as1_void;

static constexpr int D = 256;
static constexpr float INV_T = 10.0f;  // 1 / 0.1

__device__ __forceinline__ ushort f2bf(float f) {
  union { float f; unsigned u; } v; v.f = f;
  unsigned r = v.u + 0x7fffu + ((v.u >> 16) & 1u);  // RNE
  return (ushort)(r >> 16);
}

// Kernel 1: L2-normalize rows of images & captions -> bf16; diag logits (fp32).
__global__ __launch_bounds__(256) void normalize_kernel(
    const float* __restrict__ im, const float* __restrict__ cap,
    ushort* __restrict__ imn, ushort* __restrict__ capn,
    float* __restrict__ diag, int N) {
  int tid = blockIdx.x * 256 + threadIdx.x;
  int w = tid >> 6;
  int lane = threadIdx.x & 63;
  if (w >= N) return;
  float4 vi = ((const float4*)(im + (size_t)w * D))[lane];
  float4 vc = ((const float4*)(cap + (size_t)w * D))[lane];
  float ssi = vi.x*vi.x + vi.y*vi.y + vi.z*vi.z + vi.w*vi.w;
  float ssc = vc.x*vc.x + vc.y*vc.y + vc.z*vc.z + vc.w*vc.w;
  #pragma unroll
  for (int m = 1; m < 64; m <<= 1) {
    ssi += __shfl_xor(ssi, m);
    ssc += __shfl_xor(ssc, m);
  }
  float ri = 1.0f / fmaxf(sqrtf(ssi), 1e-12f);
  float rc = 1.0f / fmaxf(sqrtf(ssc), 1e-12f);
  float ax = vi.x*ri, ay = vi.y*ri, az = vi.z*ri, aw = vi.w*ri;
  float cx = vc.x*rc, cy = vc.y*rc, cz = vc.z*rc, cw = vc.w*rc;
  ushort4 ua, uc;
  ua.x = f2bf(ax); ua.y = f2bf(ay); ua.z = f2bf(az); ua.w = f2bf(aw);
  uc.x = f2bf(cx); uc.y = f2bf(cy); uc.z = f2bf(cz); uc.w = f2bf(cw);
  ((ushort4*)(imn + (size_t)w * D))[lane] = ua;
  ((ushort4*)(capn + (size_t)w * D))[lane] = uc;
  float d = ax*cx + ay*cy + az*cz + aw*cw;
  #pragma unroll
  for (int m = 1; m < 64; m <<= 1) d += __shfl_xor(d, m);
  if (lane == 0) diag[w] = d * INV_T;
}

// Kernel 2: 256x256 tile, 8 waves (2M x 4N), BK=32, double-buffered 64KB LDS
// -> 2 blocks/CU co-resident (cross-block pipe overlap covers the barrier
// lockstep). XOR swizzle for 32-elem rows: slot(row,c') holds global
// (row, c' ^ 8*((row>>1)&3)); pre-swizzled global source (linear LDS dest,
// rule 21), same involution on ds_read. Distance-1 staging: body kt_i stages
// kt_{i+1} into the non-read buffer; boundary wait folded into body-exit
// barrier (VMWAIT(0) just before it).
__global__ __launch_bounds__(512, 4) void gemm_exp_kernel(
    const ushort* __restrict__ A, const ushort* __restrict__ Bm,
    float* __restrict__ rowpart, float* __restrict__ colpart, int N) {
  __shared__ ushort As[2][256 * 32];  // 2 x 16 KB
  __shared__ ushort Bs[2][256 * 32];  // 2 x 16 KB   (64 KB total)
  int bm = blockIdx.x, bn = blockIdx.y;
  int t = threadIdx.x;
  int lane = t & 63;
  int wv = t >> 6;             // 0..7
  int wm = wv >> 2;            // 0..1 : rows [wm*128, +128)
  int wn = wv & 3;             // 0..3 : cols [wn*64, +64)

  // staging: per q-round (q=0,1), lane writes LDS slot
  //   row = q*128 + wv*16 + (lane>>2), col' = (lane&3)*8  (linear, lane*16B)
  // source col pre-swizzled: col = 8*((lane&3) ^ ((lane>>3)&3))
  //   since (row>>1)&3 == (lane>>3)&3 here.
  int srow = wv * 16 + (lane >> 2);
  int scol = 8 * ((lane & 3) ^ ((lane >> 3) & 3));
  const ushort* agbase = A + ((size_t)bm * 256 + srow) * D + scol;
  const ushort* bgbase = Bm + ((size_t)bn * 256 + srow) * D + scol;

  f32x4 acc[8][4];
  #pragma unroll
  for (int mi = 0; mi < 8; ++mi)
    #pragma unroll
    for (int ni = 0; ni < 4; ++ni)
      acc[mi][ni] = (f32x4){0.f, 0.f, 0.f, 0.f};

  int rb = lane & 15;
  int kb = (lane >> 4) * 8;
  int cc = kb ^ (((rb >> 1) & 3) * 8);  // swizzled read column (elems)

#define VMWAIT(n) asm volatile("s_waitcnt vmcnt(" #n ")" ::: "memory")
#define BARRIER() asm volatile("s_barrier" ::: "memory")

  // stage K-tile kt -> buffer buf (4 loads/wave: A q0,q1 + B q0,q1)
#define STAGE(buf, kt)                                                       \
  __builtin_amdgcn_global_load_lds(                                          \
      (as1_void*)(agbase + (kt) * 32),                                       \
      (as3_void*)(&As[buf][wv * 512]), 16, 0, 0);                            \
  __builtin_amdgcn_global_load_lds(                                          \
      (as1_void*)(agbase + (size_t)128 * D + (kt) * 32),                     \
      (as3_void*)(&As[buf][4096 + wv * 512]), 16, 0, 0);                     \
  __builtin_amdgcn_global_load_lds(                                          \
      (as1_void*)(bgbase + (kt) * 32),                                       \
      (as3_void*)(&Bs[buf][wv * 512]), 16, 0, 0);                            \
  __builtin_amdgcn_global_load_lds(                                          \
      (as1_void*)(bgbase + (size_t)128 * D + (kt) * 32),                     \
      (as3_void*)(&Bs[buf][4096 + wv * 512]), 16, 0, 0);

#define READ_B(BF, cur)                                                      \
  { _Pragma("unroll") for (int ni = 0; ni < 4; ++ni)                         \
      BF[ni] = *(const bf16x8*)(&Bs[cur][(wn * 64 + ni * 16 + rb) * 32 + cc]); }

#define READ_A(AF, cur, mh)                                                  \
  { _Pragma("unroll") for (int mi = 0; mi < 4; ++mi)                         \
      AF[mi] = *(const bf16x8*)(&As[cur][(wm * 128 + ((mh) * 4 + mi) * 16 + rb) * 32 + cc]); }

#define MF16(AF, BF, mh)                                                     \
  { __builtin_amdgcn_s_setprio(1);                                           \
    _Pragma("unroll") for (int mi = 0; mi < 4; ++mi)                         \
      _Pragma("unroll") for (int ni = 0; ni < 4; ++ni)                       \
        acc[(mh) * 4 + mi][ni] = __builtin_amdgcn_mfma_f32_16x16x32_bf16(    \
            AF[mi], BF[ni], acc[(mh) * 4 + mi][ni], 0, 0, 0);                \
    __builtin_amdgcn_s_setprio(0); }

  // Body for K-tile in buffer `cur`; S1 = stage slot (next kt, other buffer);
  // VM = boundary wait (VMWAIT(0) except last). Exit barrier doubles as the
  // residency barrier for the next tile (every wave has VMWAIT'ed its own
  // loads before it).
#define KT_BODY(cur, S1, VM)                                                 \
  {                                                                          \
    bf16x8 a0[4], a1[4], b0[4];                                              \
    READ_B(b0, cur); READ_A(a0, cur, 0);                                     \
    S1;                                                                      \
    BARRIER();                                                               \
    MF16(a0, b0, 0);                                                         \
    BARRIER();                                                               \
    READ_A(a1, cur, 1);                                                      \
    BARRIER();                                                               \
    MF16(a1, b0, 1);                                                         \
    VM;                                                                      \
    BARRIER();                                                               \
  }

  // Prologue: stage kt0 -> buf0 (oldest 4), kt1 -> buf1
  STAGE(0, 0)
  STAGE(1, 1)
  VMWAIT(4); BARRIER();                      // kt0 resident, kt1 in flight

  KT_BODY(0,            , VMWAIT(0))         // kt0
  KT_BODY(1, STAGE(0, 2), VMWAIT(0))         // kt1, stage kt2
  KT_BODY(0, STAGE(1, 3), VMWAIT(0))         // kt2, stage kt3
  KT_BODY(1, STAGE(0, 4), VMWAIT(0))         // kt3, stage kt4
  KT_BODY(0, STAGE(1, 5), VMWAIT(0))         // kt4, stage kt5
  KT_BODY(1, STAGE(0, 6), VMWAIT(0))         // kt5, stage kt6
  KT_BODY(0, STAGE(1, 7), VMWAIT(0))         // kt6, stage kt7
  KT_BODY(1,            ,           )        // kt7

#undef KT_BODY
#undef MF16
#undef READ_A
#undef READ_B
#undef STAGE

  // exp(logits); logits in [-10,10] -> safe without max subtraction
  #pragma unroll
  for (int mi = 0; mi < 8; ++mi)
    #pragma unroll
    for (int ni = 0; ni < 4; ++ni)
      #pragma unroll
      for (int r = 0; r < 4; ++r)
        acc[mi][ni][r] = __expf(acc[mi][ni][r] * INV_T);

  // C/D layout: col = lane&15, row = (lane>>4)*4 + r
  // Row sums via packed 4-value butterfly (5 shuffles per mi).
  bool sb0 = (lane & 1) != 0;
  bool sb1 = (lane & 2) != 0;
  #pragma unroll
  for (int mi = 0; mi < 8; ++mi) {
    float v0 = acc[mi][0][0] + acc[mi][1][0] + acc[mi][2][0] + acc[mi][3][0];
    float v1 = acc[mi][0][1] + acc[mi][1][1] + acc[mi][2][1] + acc[mi][3][1];
    float v2 = acc[mi][0][2] + acc[mi][1][2] + acc[mi][2][2] + acc[mi][3][2];
    float v3 = acc[mi][0][3] + acc[mi][1][3] + acc[mi][2][3] + acc[mi][3][3];
    float h0 = (sb0 ? v1 : v0) + __shfl_xor(sb0 ? v0 : v1, 1);
    float h1 = (sb0 ? v3 : v2) + __shfl_xor(sb0 ? v2 : v3, 1);
    float g  = (sb1 ? h1 : h0) + __shfl_xor(sb1 ? h0 : h1, 2);
    g += __shfl_xor(g, 4);
    g += __shfl_xor(g, 8);
    if ((lane & 12) == 0)
      rowpart[(size_t)(bn * 4 + wn) * N + bm * 256 + wm * 128 + mi * 16 +
              (lane >> 4) * 4 + (lane & 3)] = g;
  }
  // col partial sums over this wave's 128 rows -> slot (bm*2 + wm)
  #pragma unroll
  for (int ni = 0; ni < 4; ++ni) {
    float v = 0.f;
    #pragma unroll
    for (int mi = 0; mi < 8; ++mi)
      #pragma unroll
      for (int r = 0; r < 4; ++r)
        v += acc[mi][ni][r];
    v += __shfl_xor(v, 16); v += __shfl_xor(v, 32);
    if (lane < 16)
      colpart[(size_t)(bm * 2 + wm) * N + bn * 256 + wn * 64 + ni * 16 + lane] = v;
  }
#undef VMWAIT
#undef BARRIER
}

// Kernel 3: coalesced partial reduction (wave per slot residue, LDS combine).
__global__ __launch_bounds__(256) void reduce_kernel(
    const float* __restrict__ rowpart, const float* __restrict__ colpart,
    const float* __restrict__ diag, float* __restrict__ blocksum,
    int N, int NPr, int NPc) {
  __shared__ float redr[4][64], redc[4][64];
  int w = threadIdx.x >> 6, s = threadIdx.x & 63;
  int i = blockIdx.x * 64 + s;
  float rs = 0.f, cs = 0.f;
  for (int k = w; k < NPr; k += 4) rs += rowpart[(size_t)k * N + i];
  for (int k = w; k < NPc; k += 4) cs += colpart[(size_t)k * N + i];
  redr[w][s] = rs; redc[w][s] = cs;
  __syncthreads();
  if (w == 0) {
    float R = redr[0][s] + redr[1][s] + redr[2][s] + redr[3][s];
    float C = redc[0][s] + redc[1][s] + redc[2][s] + redc[3][s];
    float l = logf(R) + logf(C) - 2.0f * diag[i];
    #pragma unroll
    for (int m = 1; m < 64; m <<= 1) l += __shfl_xor(l, m);
    if (s == 0) blocksum[blockIdx.x] = l;
  }
}

// Kernel 4: final mean over 128 block sums
__global__ __launch_bounds__(128) void final_kernel(
    const float* __restrict__ blocksum, float* __restrict__ out, int N) {
  __shared__ float red[2];
  float v = blocksum[threadIdx.x];
  #pragma unroll
  for (int m = 1; m < 64; m <<= 1) v += __shfl_xor(v, m);
  if ((threadIdx.x & 63) == 0) red[threadIdx.x >> 6] = v;
  __syncthreads();
  if (threadIdx.x == 0) out[0] = (red[0] + red[1]) * (0.5f / (float)N);
}

extern "C" void kernel_launch(void* const* d_in, const int* in_sizes, int n_in,
                              void* d_out, int out_size, void* d_ws, size_t ws_size,
                              hipStream_t stream) {
  const float* images = (const float*)d_in[0];
  const float* captions = (const float*)d_in[1];
  int N = in_sizes[0] / D;   // 8192
  int NB = N / 256;          // 32 tile-blocks per dim
  int NPr = NB * 4;          // 128 row-partial slots
  int NPc = NB * 2;          // 64 col-partial slots
  char* w = (char*)d_ws;
  size_t off = 0;
  ushort* imn  = (ushort*)(w + off); off += (size_t)N * D * 2;
  ushort* capn = (ushort*)(w + off); off += (size_t)N * D * 2;
  float* diag    = (float*)(w + off); off += (size_t)N * 4;
  float* rowpart = (float*)(w + off); off += (size_t)NPr * N * 4;
  float* colpart = (float*)(w + off); off += (size_t)NPc * N * 4;
  float* blocksum = (float*)(w + off); off += 1024;
  float* out = (float*)d_out;

  normalize_kernel<<<N / 4, 256, 0, stream>>>(images, captions, imn, capn, diag, N);
  dim3 g(NB, NB);
  gemm_exp_kernel<<<g, 512, 0, stream>>>(imn, capn, rowpart, colpart, N);
  reduce_kernel<<<N / 64, 256, 0, stream>>>(rowpart, colpart, diag, blocksum, N, NPr, NPc);
  final_kernel<<<1, 128, 0, stream>>>(blocksum, out, N);
}

// Round 8
// 69.647 us; speedup vs baseline: 4.7548x; 4.7548x over previous
//
#include <hip/hip_runtime.h>
#include <hip/hip_bf16.h>

typedef short bf16x8 __attribute__((ext_vector_type(8)));
typedef float f32x4 __attribute__((ext_vector_type(4)));

typedef __attribute__((address_space(3))) void as3_void;
typedef const __attribute__((address_space(1))) void as1_void;

static constexpr int D = 256;
static constexpr float INV_T = 10.0f;  // 1 / 0.1

__device__ __forceinline__ ushort f2bf(float f) {
  union { float f; unsigned u; } v; v.f = f;
  unsigned r = v.u + 0x7fffu + ((v.u >> 16) & 1u);  // RNE
  return (ushort)(r >> 16);
}

// Kernel 1: L2-normalize rows of images & captions -> bf16; diag logits (fp32).
__global__ __launch_bounds__(256) void normalize_kernel(
    const float* __restrict__ im, const float* __restrict__ cap,
    ushort* __restrict__ imn, ushort* __restrict__ capn,
    float* __restrict__ diag, int N) {
  int tid = blockIdx.x * 256 + threadIdx.x;
  int w = tid >> 6;
  int lane = threadIdx.x & 63;
  if (w >= N) return;
  float4 vi = ((const float4*)(im + (size_t)w * D))[lane];
  float4 vc = ((const float4*)(cap + (size_t)w * D))[lane];
  float ssi = vi.x*vi.x + vi.y*vi.y + vi.z*vi.z + vi.w*vi.w;
  float ssc = vc.x*vc.x + vc.y*vc.y + vc.z*vc.z + vc.w*vc.w;
  #pragma unroll
  for (int m = 1; m < 64; m <<= 1) {
    ssi += __shfl_xor(ssi, m);
    ssc += __shfl_xor(ssc, m);
  }
  float ri = 1.0f / fmaxf(sqrtf(ssi), 1e-12f);
  float rc = 1.0f / fmaxf(sqrtf(ssc), 1e-12f);
  float ax = vi.x*ri, ay = vi.y*ri, az = vi.z*ri, aw = vi.w*ri;
  float cx = vc.x*rc, cy = vc.y*rc, cz = vc.z*rc, cw = vc.w*rc;
  ushort4 ua, uc;
  ua.x = f2bf(ax); ua.y = f2bf(ay); ua.z = f2bf(az); ua.w = f2bf(aw);
  uc.x = f2bf(cx); uc.y = f2bf(cy); uc.z = f2bf(cz); uc.w = f2bf(cw);
  ((ushort4*)(imn + (size_t)w * D))[lane] = ua;
  ((ushort4*)(capn + (size_t)w * D))[lane] = uc;
  float d = ax*cx + ay*cy + az*cz + aw*cw;
  #pragma unroll
  for (int m = 1; m < 64; m <<= 1) d += __shfl_xor(d, m);
  if (lane == 0) diag[w] = d * INV_T;
}

// Kernel 2: persistent GEMM. Grid = 256 blocks (1/CU); block owns bm and 4
// bn-tiles (one 32-kt pipeline). A (bm, all K) resident in 128KB LDS, staged
// once; B double-buffered 2x16KB (total 160KB). BK=32; 8 waves (2M x 4N).
// Swizzle (HW-verified r7): slot(row,u16) holds global(row, u16 ^ ((row>>1)&3));
// linear gload_lds dest + pre-swizzled global source + swizzled ds_read.
// Counted vmcnt(2) everywhere; every kt stages B(kt+2) in its phase 2
// (own-buffer staging legal: B reads consumed before preceding barrier).
__global__ __launch_bounds__(512) void gemm_exp_kernel(
    const ushort* __restrict__ A, const ushort* __restrict__ Bm,
    float* __restrict__ rowpart, float* __restrict__ colpart, int N) {
  __shared__ ushort As[8][256 * 32];  // 8 x 16 KB = 128 KB (A resident, per kt)
  __shared__ ushort Bs[2][256 * 32];  // 2 x 16 KB (B double buffer)
  int bm = blockIdx.x >> 3;
  int bn0 = (blockIdx.x & 7) * 4;
  int t = threadIdx.x;
  int lane = t & 63;
  int wv = t >> 6;             // 0..7
  int wm = wv >> 2;            // 0..1 : rows [wm*128, +128)
  int wn = wv & 3;             // 0..3 : cols [wn*64, +64)

  // staging: per q (0/1), lane writes LDS slot row = q*128 + wv*16 + (lane>>2),
  // 16B-unit u = lane&3 (linear). Global source unit = u ^ ((row>>1)&3)
  //   = (lane&3) ^ ((lane>>3)&3).
  int srow = wv * 16 + (lane >> 2);
  int scol = 8 * ((lane & 3) ^ ((lane >> 3) & 3));
  const ushort* agbase = A + ((size_t)bm * 256 + srow) * D + scol;

  f32x4 acc[8][4];
  #pragma unroll
  for (int mi = 0; mi < 8; ++mi)
    #pragma unroll
    for (int ni = 0; ni < 4; ++ni)
      acc[mi][ni] = (f32x4){0.f, 0.f, 0.f, 0.f};

  int rb = lane & 15;
  int kb = (lane >> 4) * 8;
  int cc = kb ^ (((rb >> 1) & 3) * 8);  // swizzled read column (elems)

#define VMWAIT(n) asm volatile("s_waitcnt vmcnt(" #n ")" ::: "memory")
#define BARRIER() asm volatile("s_barrier" ::: "memory")

#define STAGE_A(kt)                                                          \
  __builtin_amdgcn_global_load_lds(                                          \
      (as1_void*)(agbase + (kt) * 32),                                       \
      (as3_void*)(&As[kt][wv * 512]), 16, 0, 0);                             \
  __builtin_amdgcn_global_load_lds(                                          \
      (as1_void*)(agbase + (size_t)128 * D + (kt) * 32),                     \
      (as3_void*)(&As[kt][4096 + wv * 512]), 16, 0, 0);

#define STAGE_B(buf, gptr, kt)                                               \
  __builtin_amdgcn_global_load_lds(                                          \
      (as1_void*)((gptr) + (kt) * 32),                                       \
      (as3_void*)(&Bs[buf][wv * 512]), 16, 0, 0);                            \
  __builtin_amdgcn_global_load_lds(                                          \
      (as1_void*)((gptr) + (size_t)128 * D + (kt) * 32),                     \
      (as3_void*)(&Bs[buf][4096 + wv * 512]), 16, 0, 0);

#define READ_B(BF, buf)                                                      \
  { _Pragma("unroll") for (int ni = 0; ni < 4; ++ni)                         \
      BF[ni] = *(const bf16x8*)(&Bs[buf][(wn * 64 + ni * 16 + rb) * 32 + cc]); }

#define READ_A(AF, kt, mh)                                                   \
  { _Pragma("unroll") for (int mi = 0; mi < 4; ++mi)                         \
      AF[mi] = *(const bf16x8*)(&As[kt][(wm * 128 + ((mh) * 4 + mi) * 16 + rb) * 32 + cc]); }

#define MF16(AF, BF, mh)                                                     \
  { __builtin_amdgcn_s_setprio(1);                                           \
    _Pragma("unroll") for (int mi = 0; mi < 4; ++mi)                         \
      _Pragma("unroll") for (int ni = 0; ni < 4; ++ni)                       \
        acc[(mh) * 4 + mi][ni] = __builtin_amdgcn_mfma_f32_16x16x32_bf16(    \
            AF[mi], BF[ni], acc[(mh) * 4 + mi][ni], 0, 0, 0);                \
    __builtin_amdgcn_s_setprio(0); }

  // K-tile body: phase1 {read B+A0; BAR; MFMA0}; phase2 {read A1; stage S;
  // BAR; MFMA1; W; BAR}. S into Bs[kt&1] is legal: that buffer's B-reads were
  // consumed (lgkm-waited) before the barrier preceding S.
#define KT_BODY(kt, S, W)                                                    \
  {                                                                          \
    bf16x8 a0[4], a1[4], b0[4];                                              \
    READ_B(b0, (kt) & 1); READ_A(a0, kt, 0);                                 \
    BARRIER();                                                               \
    MF16(a0, b0, 0);                                                         \
    BARRIER();                                                               \
    READ_A(a1, kt, 1);                                                       \
    S;                                                                       \
    BARRIER();                                                               \
    MF16(a1, b0, 1);                                                         \
    W;                                                                       \
    BARRIER();                                                               \
  }

  // Prologue: A-all (16 loads/thread) + B(tile0,kt0) + B(tile0,kt1)
  {
    const ushort* bg0 = Bm + ((size_t)bn0 * 256 + srow) * D + scol;
    #pragma unroll
    for (int kt = 0; kt < 8; ++kt) { STAGE_A(kt) }
    STAGE_B(0, bg0, 0)
    STAGE_B(1, bg0, 1)
  }
  VMWAIT(2); BARRIER();   // A + B(0,0) resident; B(0,1) in flight

  for (int j = 0; j < 4; ++j) {
    int bn_cur = bn0 + j;
    int bn_nxt = bn0 + ((j + 1) & 3);
    const ushort* bgc = Bm + ((size_t)bn_cur * 256 + srow) * D + scol;
    const ushort* bgn = Bm + ((size_t)bn_nxt * 256 + srow) * D + scol;

    // Ledger (per thread, entering kt0): outstanding = B(j,1)(2).
    // Each kt stages kt+2 (2 loads) then waits vmcnt(2) -> kt+1 resident,
    // kt+2 in flight. Never drains; waited loads are >=1.5 kt old.
    KT_BODY(0, STAGE_B(0, bgc, 2), VMWAIT(2))
    KT_BODY(1, STAGE_B(1, bgc, 3), VMWAIT(2))
    KT_BODY(2, STAGE_B(0, bgc, 4), VMWAIT(2))
    KT_BODY(3, STAGE_B(1, bgc, 5), VMWAIT(2))
    KT_BODY(4, STAGE_B(0, bgc, 6), VMWAIT(2))
    KT_BODY(5, STAGE_B(1, bgc, 7), VMWAIT(2))
    KT_BODY(6, STAGE_B(0, bgn, 0), VMWAIT(2))   // next tile kt0 -> b0
    KT_BODY(7, STAGE_B(1, bgn, 1), VMWAIT(4))   // next tile kt1 -> b1; no wait
    // (last tile wraps bgn to tile 0: harmless valid restage)

    // Epilogue for tile j (no LDS use; next-tile loads fly underneath).
    // exp(logits); logits in [-10,10] -> safe without max subtraction.
    #pragma unroll
    for (int mi = 0; mi < 8; ++mi)
      #pragma unroll
      for (int ni = 0; ni < 4; ++ni)
        #pragma unroll
        for (int r = 0; r < 4; ++r)
          acc[mi][ni][r] = __expf(acc[mi][ni][r] * INV_T);

    // C/D layout: col = lane&15, row = (lane>>4)*4 + r
    // Row sums via packed 4-value butterfly (5 shuffles per mi).
    bool sb0 = (lane & 1) != 0;
    bool sb1 = (lane & 2) != 0;
    #pragma unroll
    for (int mi = 0; mi < 8; ++mi) {
      float v0 = acc[mi][0][0] + acc[mi][1][0] + acc[mi][2][0] + acc[mi][3][0];
      float v1 = acc[mi][0][1] + acc[mi][1][1] + acc[mi][2][1] + acc[mi][3][1];
      float v2 = acc[mi][0][2] + acc[mi][1][2] + acc[mi][2][2] + acc[mi][3][2];
      float v3 = acc[mi][0][3] + acc[mi][1][3] + acc[mi][2][3] + acc[mi][3][3];
      float h0 = (sb0 ? v1 : v0) + __shfl_xor(sb0 ? v0 : v1, 1);
      float h1 = (sb0 ? v3 : v2) + __shfl_xor(sb0 ? v2 : v3, 1);
      float g  = (sb1 ? h1 : h0) + __shfl_xor(sb1 ? h0 : h1, 2);
      g += __shfl_xor(g, 4);
      g += __shfl_xor(g, 8);
      if ((lane & 12) == 0)
        rowpart[(size_t)(bn_cur * 4 + wn) * N + bm * 256 + wm * 128 + mi * 16 +
                (lane >> 4) * 4 + (lane & 3)] = g;
    }
    // col partial sums over this wave's 128 rows -> slot (bm*2 + wm)
    #pragma unroll
    for (int ni = 0; ni < 4; ++ni) {
      float v = 0.f;
      #pragma unroll
      for (int mi = 0; mi < 8; ++mi)
        #pragma unroll
        for (int r = 0; r < 4; ++r)
          v += acc[mi][ni][r];
      v += __shfl_xor(v, 16); v += __shfl_xor(v, 32);
      if (lane < 16)
        colpart[(size_t)(bm * 2 + wm) * N + bn_cur * 256 + wn * 64 + ni * 16 + lane] = v;
    }
    // reset accumulators for next tile
    #pragma unroll
    for (int mi = 0; mi < 8; ++mi)
      #pragma unroll
      for (int ni = 0; ni < 4; ++ni)
        acc[mi][ni] = (f32x4){0.f, 0.f, 0.f, 0.f};

    VMWAIT(2); BARRIER();   // next tile's kt0 resident, kt1 in flight
  }
  VMWAIT(0);  // retire stray staging loads before endpgm

#undef KT_BODY
#undef MF16
#undef READ_A
#undef READ_B
#undef STAGE_A
#undef STAGE_B
#undef VMWAIT
#undef BARRIER
}

// Kernel 3: coalesced partial reduction (wave per slot residue, LDS combine).
__global__ __launch_bounds__(256) void reduce_kernel(
    const float* __restrict__ rowpart, const float* __restrict__ colpart,
    const float* __restrict__ diag, float* __restrict__ blocksum,
    int N, int NPr, int NPc) {
  __shared__ float redr[4][64], redc[4][64];
  int w = threadIdx.x >> 6, s = threadIdx.x & 63;
  int i = blockIdx.x * 64 + s;
  float rs = 0.f, cs = 0.f;
  for (int k = w; k < NPr; k += 4) rs += rowpart[(size_t)k * N + i];
  for (int k = w; k < NPc; k += 4) cs += colpart[(size_t)k * N + i];
  redr[w][s] = rs; redc[w][s] = cs;
  __syncthreads();
  if (w == 0) {
    float R = redr[0][s] + redr[1][s] + redr[2][s] + redr[3][s];
    float C = redc[0][s] + redc[1][s] + redc[2][s] + redc[3][s];
    float l = logf(R) + logf(C) - 2.0f * diag[i];
    #pragma unroll
    for (int m = 1; m < 64; m <<= 1) l += __shfl_xor(l, m);
    if (s == 0) blocksum[blockIdx.x] = l;
  }
}

// Kernel 4: final mean over 128 block sums
__global__ __launch_bounds__(128) void final_kernel(
    const float* __restrict__ blocksum, float* __restrict__ out, int N) {
  __shared__ float red[2];
  float v = blocksum[threadIdx.x];
  #pragma unroll
  for (int m = 1; m < 64; m <<= 1) v += __shfl_xor(v, m);
  if ((threadIdx.x & 63) == 0) red[threadIdx.x >> 6] = v;
  __syncthreads();
  if (threadIdx.x == 0) out[0] = (red[0] + red[1]) * (0.5f / (float)N);
}

extern "C" void kernel_launch(void* const* d_in, const int* in_sizes, int n_in,
                              void* d_out, int out_size, void* d_ws, size_t ws_size,
                              hipStream_t stream) {
  const float* images = (const float*)d_in[0];
  const float* captions = (const float*)d_in[1];
  int N = in_sizes[0] / D;   // 8192
  int NB = N / 256;          // 32 tile-blocks per dim
  int NPr = NB * 4;          // 128 row-partial slots
  int NPc = NB * 2;          // 64 col-partial slots
  char* w = (char*)d_ws;
  size_t off = 0;
  ushort* imn  = (ushort*)(w + off); off += (size_t)N * D * 2;
  ushort* capn = (ushort*)(w + off); off += (size_t)N * D * 2;
  float* diag    = (float*)(w + off); off += (size_t)N * 4;
  float* rowpart = (float*)(w + off); off += (size_t)NPr * N * 4;
  float* colpart = (float*)(w + off); off += (size_t)NPc * N * 4;
  float* blocksum = (float*)(w + off); off += 1024;
  float* out = (float*)d_out;

  normalize_kernel<<<N / 4, 256, 0, stream>>>(images, captions, imn, capn, diag, N);
  gemm_exp_kernel<<<NB * 8, 512, 0, stream>>>(imn, capn, rowpart, colpart, N);
  reduce_kernel<<<N / 64, 256, 0, stream>>>(rowpart, colpart, diag, blocksum, N, NPr, NPc);
  final_kernel<<<1, 128, 0, stream>>>(blocksum, out, N);
}